// Round 10
// baseline (269.358 us; speedup 1.0000x reference)
//
#include <hip/hip_runtime.h>
#include <cstdint>

#define Ltok 4096
#define Dm   2048

typedef __attribute__((ext_vector_type(8))) short short8;
typedef __attribute__((ext_vector_type(4))) float f32x4;

static __device__ __forceinline__ ushort f2bf(float x) {
  union { float f; uint32_t u; } v; v.f = x;
  uint32_t r = v.u + 0x7FFFu + ((v.u >> 16) & 1u);
  return (ushort)(r >> 16);
}

typedef __attribute__((address_space(1))) void gv_t;
typedef __attribute__((address_space(3))) void lv_t;
static __device__ __forceinline__ void lds_load16(const void* g, void* l) {
  __builtin_amdgcn_global_load_lds((gv_t*)g, (lv_t*)l, 16, 0, 0);
}

// ---------------------------------------------------------------------------
__global__ __launch_bounds__(256) void prep_tokens(const float* __restrict__ T,
                                                   const float* __restrict__ ecc,
                                                   const int* __restrict__ pos,
                                                   const int* __restrict__ dep,
                                                   ushort* __restrict__ Tbf,
                                                   float4* __restrict__ tokf4) {
  __shared__ float red[4];
  const int tid = threadIdx.x, lane = tid & 63, w = tid >> 6;
  const int row = blockIdx.x;
  const float* rp = T + (size_t)row * Dm;
  ushort* op = Tbf + (size_t)row * Dm;
  float ss = 0.f;
  for (int j = tid * 4; j < Dm; j += 1024) {
    float4 v = *(const float4*)&rp[j];
    ss += v.x * v.x + v.y * v.y + v.z * v.z + v.w * v.w;
    ushort4 o; o.x = f2bf(v.x); o.y = f2bf(v.y); o.z = f2bf(v.z); o.w = f2bf(v.w);
    *(ushort4*)&op[j] = o;
  }
#pragma unroll
  for (int off = 32; off > 0; off >>= 1) ss += __shfl_xor(ss, off);
  if (lane == 0) red[w] = ss;
  __syncthreads();
  if (tid == 0) {
    float n = sqrtf(red[0] + red[1] + red[2] + red[3]);
    int d = dep[row];
    float4 t;
    t.x = n / (n + 1e-8f);
    t.y = ecc[row];
    t.z = (d <= 0) ? 1.0f : (d == 1 ? 3.0f : 9.0f);
    t.w = (float)pos[row];
    tokf4[row] = t;
  }
}

__global__ __launch_bounds__(256) void cast_f32_bf16(const float* __restrict__ in,
                                                     ushort* __restrict__ out, int n) {
  int i = (blockIdx.x * 256 + threadIdx.x) * 4;
  if (i + 3 < n) {
    float4 v = *(const float4*)&in[i];
    ushort4 o; o.x = f2bf(v.x); o.y = f2bf(v.y); o.z = f2bf(v.z); o.w = f2bf(v.w);
    *(ushort4*)&out[i] = o;
  }
}

__global__ void small_prep(const float* __restrict__ G, const float* __restrict__ R,
                           float* __restrict__ sGR) {
  int tid = threadIdx.x;
  if (tid < 64) {
    float g = 1.0f / (1.0f + expf(-G[tid]));
    float r = 1.0f / (1.0f + expf(-R[tid]));
    sGR[tid] = g * r;
  }
}

// ---------------------------------------------------------------------------
#define FENCE asm volatile("" ::: "memory")
#define PH_MID { FENCE; __builtin_amdgcn_s_barrier(); __builtin_amdgcn_s_setprio(1); }
#define PH_END { __builtin_amdgcn_s_setprio(0); FENCE; __builtin_amdgcn_s_barrier(); FENCE; }
#define PH_ENDV1 { __builtin_amdgcn_s_setprio(0); FENCE; \
                  asm volatile("s_waitcnt vmcnt(1)" ::: "memory"); \
                  __builtin_amdgcn_s_barrier(); FENCE; }
#define PH_ENDV2 { __builtin_amdgcn_s_setprio(0); FENCE; \
                  asm volatile("s_waitcnt vmcnt(2)" ::: "memory"); \
                  __builtin_amdgcn_s_barrier(); FENCE; }

// inverse st_16x32 swizzle within a 16KB unit (8KB halves x 2 col-blocks)
#define INV_SWZ(P, ROW, COL) { \
  int s_ = (P) >> 10, ww_ = (P) & 1023; \
  ww_ ^= ((ww_ >> 9) & 1) << 5; \
  ROW = ((s_ >> 1) << 4) + (ww_ >> 6); \
  COL = ((s_ & 1) << 5) + ((ww_ >> 1) & 31); }

// inverse st_16x32 swizzle within an 8KB unit ([128 rows][32 cols] bf16)
#define INV_SWZ8(P, ROW, COL) { \
  int s_ = (P) >> 10, ww_ = (P) & 1023; \
  ww_ ^= ((ww_ >> 9) & 1) << 5; \
  ROW = (s_ << 4) + (ww_ >> 6); \
  COL = (ww_ >> 1) & 31; }

// ===========================================================================
// gemm4b: 128x256 tile, BK=32, 8 waves (2Mx4N, 64x64 C/wave), 4-phase,
// 48KB LDS double-buffer, target 2 blocks/CU.
// Buf layout (24576B stride): A [128][32] 8KB @0; B [256][32] 16KB @8192
// (two 8KB halves by N-rows 0-127 / 128-255).
// Loads/iter (per thread): P1:2 (buf1.B<-t1) P2:1 (buf0.A<-t2)
//   P3:2 (buf0.B<-t2) P4:1 (buf1.A<-t3).
// Drains: vmcnt(1) @P2-end (completes buf1: prev-P4 A + P1 B),
//         vmcnt(1) @P4-end (completes buf0-t2: P2 A + P3 B).
#define STB_A(BUF,KT) \
  lds_load16(sAs + (size_t)(KT)*32, lbase + (BUF)*24576 + tid*16);
#define STB_BH(BUF,H,KT) \
  lds_load16(sBs + (size_t)(H)*128*KDIM + (size_t)(KT)*32, lbase + (BUF)*24576 + 8192 + (H)*8192 + tid*16);
#define RDB_A(BUF) { _Pragma("unroll") for (int m_ = 0; m_ < 4; ++m_) \
    a[m_] = *(const short8*)(lbase + (BUF)*24576 + baseA + m_*1024); }
#define RDB_B(BUF,NIB) { _Pragma("unroll") for (int n_ = 0; n_ < 2; ++n_) \
    b[n_] = *(const short8*)(lbase + (BUF)*24576 + baseB + ((NIB)+n_)*1024); }
#define MFB_P(NIB) { _Pragma("unroll") for (int m_ = 0; m_ < 4; ++m_) \
  _Pragma("unroll") for (int n_ = 0; n_ < 2; ++n_) \
    acc[m_][(NIB)+n_] = __builtin_amdgcn_mfma_f32_16x16x32_bf16(a[m_], b[n_], acc[m_][(NIB)+n_], 0, 0, 0); }

// MODE 0: scores epilogue -> f32 (c_ij scale, zero diag)
template <int MODE, int NDIM, int KDIM>
__global__ __launch_bounds__(512, 4) void gemm4b(
    const ushort* __restrict__ A, const ushort* __restrict__ B,
    float* __restrict__ Cf,
    const float4* __restrict__ tokf4, const float* __restrict__ sGR)
{
  constexpr int NT = KDIM / 32;
  constexpr int NI = NT / 2;
  __shared__ __align__(16) char lds_raw[49152];
  char* lbase = lds_raw;

  const int tid = threadIdx.x;
  const int lane = tid & 63;
  const int w0 = tid >> 6;
  const int wr = w0 >> 2, wc = w0 & 3;
  const int fr = lane & 15, fq = lane >> 4;

  int gx = gridDim.x;
  int bid = blockIdx.y * gx + blockIdx.x;
  int cpx = (gx * gridDim.y) >> 3;
  int sbid = (bid & 7) * cpx + (bid >> 3);
  const int bn = (sbid % gx) * 256;
  const int bm = (sbid / gx) * 128;

  int rS, cS;
  INV_SWZ8(tid * 16, rS, cS)
  const ushort* sAs = A + (size_t)(bm + rS) * KDIM + cS;
  const ushort* sBs = B + (size_t)(bn + rS) * KDIM + cS;

  const int lanep = (fr * 64 + fq * 16) ^ ((fr & 8) << 2);
  const int baseA = wr * 4096 + lanep;
  const int baseB = 8192 + wc * 4096 + lanep;

  short8 a[4], b[2];
  f32x4 acc[4][4] = {};

  // prologue: buf0 <- t0 (A + 2 B-halves), buf1.A <- t1
  STB_A(0, 0) STB_BH(0, 0, 0) STB_BH(0, 1, 0)
  STB_A(1, 1)
  FENCE;
  asm volatile("s_waitcnt vmcnt(1)" ::: "memory");
  __builtin_amdgcn_s_barrier();
  FENCE;

#pragma unroll 1
  for (int it = 0; it < NI; ++it) {
    const int t1 = 2 * it + 1;
    const int t2 = (2 * it + 2 < NT) ? 2 * it + 2 : NT - 1;
    const int t3 = (2 * it + 3 < NT) ? 2 * it + 3 : NT - 1;
    // P1: rd buf0 {A m0-3, B n0-1}; stage buf1.B <- t1 (B dead since prev P4)
    RDB_A(0) RDB_B(0, 0) STB_BH(1, 0, t1) STB_BH(1, 1, t1)
    PH_MID MFB_P(0) PH_END
    // P2: rd buf0 B n2-3; stage buf0.A <- t2 (A dead after P1); drain buf1
    RDB_B(0, 2) STB_A(0, t2)
    PH_MID MFB_P(2) PH_ENDV1
    // P3: rd buf1 {A, B n0-1}; stage buf0.B <- t2 (B dead after P2)
    RDB_A(1) RDB_B(1, 0) STB_BH(0, 0, t2) STB_BH(0, 1, t2)
    PH_MID MFB_P(0) PH_END
    // P4: rd buf1 B n2-3; stage buf1.A <- t3 (A dead after P3); drain buf0
    RDB_B(1, 2) STB_A(1, t3)
    PH_MID MFB_P(2) PH_ENDV1
  }

  // ---- epilogue (MODE 0: scores) ----
  const int gj0 = bn + wc * 64 + fr;
  const int gi0 = bm + wr * 64 + fq * 4;
  float4 cj[4];
#pragma unroll
  for (int n = 0; n < 4; ++n) cj[n] = tokf4[gj0 + n * 16];
#pragma unroll
  for (int m = 0; m < 4; ++m) {
#pragma unroll
    for (int r = 0; r < 4; ++r) {
      const int gi = gi0 + m * 16 + r;
      float4 ci = tokf4[gi];
#pragma unroll
      for (int n = 0; n < 4; ++n) {
        const int gj = gj0 + n * 16;
        float x = acc[m][n][r];
        float rr = fabsf(ci.z - cj[n].z) + 1.0f;
        int pi = (int)ci.w, pj = (int)cj[n].w;
        float c = sGR[pi * 8 + pj] * (1.0f - ci.y * cj[n].y) *
                  (ci.x * cj[n].x) * __builtin_amdgcn_rcpf(rr * rr);
        x *= c;
        if (gi == gj) x = 0.0f;
        Cf[(size_t)gi * NDIM + gj] = x;
      }
    }
  }
}

// ===========================================================================
// gemm4: 128x256 tile (BK=64, 8 waves 2Mx4N, per-wave 64x64), 4-phase.
// (round-6 proven form, unchanged)
#define ST_A4(BUF,KT) { \
  lds_load16(sA0 + (size_t)(KT)*64, lbase + (BUF)*49152 + stW); \
  lds_load16(sA1 + (size_t)(KT)*64, lbase + (BUF)*49152 + 8192 + stW); }
#define ST_B4(BUF,H,KT) { \
  lds_load16(sB0 + (size_t)(H)*128*KDIM + (size_t)(KT)*64, lbase + (BUF)*49152 + 16384 + (H)*16384 + stW); \
  lds_load16(sB1 + (size_t)(H)*128*KDIM + (size_t)(KT)*64, lbase + (BUF)*49152 + 16384 + (H)*16384 + 8192 + stW); }
#define DS_A4(BUF) { _Pragma("unroll") for (int m_ = 0; m_ < 4; ++m_) \
  _Pragma("unroll") for (int kk_ = 0; kk_ < 2; ++kk_) \
    a[m_][kk_] = *(const short8*)(lbase + (BUF)*49152 + baseA + m_*2048 + kk_*1024); }
#define DS_B4(BUF,NIB) { _Pragma("unroll") for (int n_ = 0; n_ < 2; ++n_) \
  _Pragma("unroll") for (int kk_ = 0; kk_ < 2; ++kk_) \
    bq[(NIB)+n_][kk_] = *(const short8*)(lbase + (BUF)*49152 + 16384 + baseB + ((NIB)+n_)*2048 + kk_*1024); }
#define MFMA_Q4(NIB) { _Pragma("unroll") for (int m_ = 0; m_ < 4; ++m_) \
  _Pragma("unroll") for (int n_ = 0; n_ < 2; ++n_) { \
    acc[m_][(NIB)+n_] = __builtin_amdgcn_mfma_f32_16x16x32_bf16(a[m_][0], bq[(NIB)+n_][0], acc[m_][(NIB)+n_], 0, 0, 0); \
    acc[m_][(NIB)+n_] = __builtin_amdgcn_mfma_f32_16x16x32_bf16(a[m_][1], bq[(NIB)+n_][1], acc[m_][(NIB)+n_], 0, 0, 0); } }

// MODE 1: +row bias -> bf16.  MODE 2: plain -> bf16.  MODE 3: +col bias -> f32.
template <int MODE, int NDIM, int KDIM>
__global__ __launch_bounds__(512, 2) void gemm4(
    const ushort* __restrict__ A, const ushort* __restrict__ B,
    float* __restrict__ Cf, ushort* __restrict__ Cbf,
    const float* __restrict__ bias)
{
  constexpr int NT = KDIM / 64;
  constexpr int NI = NT / 2;
  __shared__ __align__(16) char lds_raw[98304];
  char* lbase = lds_raw;

  const int tid = threadIdx.x;
  const int lane = tid & 63;
  const int w0 = tid >> 6;
  const int wr = w0 >> 2, wc = w0 & 3;
  const int fr = lane & 15, fq = lane >> 4;

  int gx = gridDim.x;
  int bid = blockIdx.y * gx + blockIdx.x;
  int cpx = (gx * gridDim.y) >> 3;
  int sbid = (bid & 7) * cpx + (bid >> 3);
  const int bn = (sbid % gx) * 256;
  const int bm = (sbid / gx) * 128;

  int rA0, cA0, rA1, cA1;
  INV_SWZ(tid * 16, rA0, cA0)
  INV_SWZ(tid * 16 + 8192, rA1, cA1)
  const ushort* sA0 = A + (size_t)(bm + rA0) * KDIM + cA0;
  const ushort* sA1 = A + (size_t)(bm + rA1) * KDIM + cA1;
  const ushort* sB0 = B + (size_t)(bn + rA0) * KDIM + cA0;
  const ushort* sB1 = B + (size_t)(bn + rA1) * KDIM + cA1;
  const int stW = w0 * 1024;

  const int lanep = (fr * 64 + fq * 16) ^ ((fr & 8) << 2);
  const int baseA = wr * 8192 + lanep;
  const int baseB = wc * 8192 + lanep;

  short8 a[4][2], bq[4][2];
  f32x4 acc[4][4] = {};

  ST_A4(0, 0) ST_B4(0, 0, 0) ST_B4(0, 1, 0)
  ST_A4(1, 1)
  FENCE;
  asm volatile("s_waitcnt vmcnt(2)" ::: "memory");
  __builtin_amdgcn_s_barrier();
  FENCE;

#pragma unroll 1
  for (int it = 0; it < NI; ++it) {
    const int t1 = 2 * it + 1;
    const int t2 = (2 * it + 2 < NT) ? 2 * it + 2 : NT - 1;
    const int t3 = (2 * it + 3 < NT) ? 2 * it + 3 : NT - 1;
    DS_A4(0) DS_B4(0, 0) ST_B4(1, 0, t1) ST_B4(1, 1, t1)
    PH_MID MFMA_Q4(0) PH_END
    DS_B4(0, 2) ST_A4(0, t2)
    PH_MID MFMA_Q4(2) PH_ENDV2
    DS_A4(1) DS_B4(1, 0) ST_B4(0, 0, t2) ST_B4(0, 1, t2)
    PH_MID MFMA_Q4(0) PH_END
    DS_B4(1, 2) ST_A4(1, t3)
    PH_MID MFMA_Q4(2) PH_ENDV2
  }

  // ---- epilogue ----
  const int gj0 = bn + wc * 64 + fr;
  const int gi0 = bm + wr * 64 + fq * 4;

  if constexpr (MODE == 1) {
#pragma unroll
    for (int m = 0; m < 4; ++m) {
#pragma unroll
      for (int r = 0; r < 4; ++r) {
        const int gi = gi0 + m * 16 + r;
        float rb = bias[gi];
#pragma unroll
        for (int n = 0; n < 4; ++n)
          Cbf[(size_t)gi * NDIM + gj0 + n * 16] = f2bf(acc[m][n][r] + rb);
      }
    }
  } else if constexpr (MODE == 2) {
#pragma unroll
    for (int m = 0; m < 4; ++m)
#pragma unroll
      for (int r = 0; r < 4; ++r) {
        const int gi = gi0 + m * 16 + r;
#pragma unroll
        for (int n = 0; n < 4; ++n)
          Cbf[(size_t)gi * NDIM + gj0 + n * 16] = f2bf(acc[m][n][r]);
      }
  } else {
    float cb[4];
#pragma unroll
    for (int n = 0; n < 4; ++n) cb[n] = bias[gj0 + n * 16];
#pragma unroll
    for (int m = 0; m < 4; ++m)
#pragma unroll
      for (int r = 0; r < 4; ++r) {
        const int gi = gi0 + m * 16 + r;
#pragma unroll
        for (int n = 0; n < 4; ++n)
          Cf[(size_t)gi * NDIM + gj0 + n * 16] = acc[m][n][r] + cb[n];
      }
  }
}

// ---------------------------------------------------------------------------
__global__ __launch_bounds__(256) void softmax_rows(const float* __restrict__ S,
                                                    float* __restrict__ Af,
                                                    ushort* __restrict__ Abf) {
  __shared__ float buf[Ltok];
  __shared__ float red[4];
  const int tid = threadIdx.x, lane = tid & 63, w = tid >> 6;
  const float LOG2E = 1.44269504088896f;
  const float* sr = S + (size_t)blockIdx.x * Ltok;
  float lmax = -3.4e38f;
  for (int j = tid * 4; j < Ltok; j += 1024) {
    float4 v = *(const float4*)&sr[j];
    *(float4*)&buf[j] = v;
    lmax = fmaxf(fmaxf(lmax, fmaxf(v.x, v.y)), fmaxf(v.z, v.w));
  }
#pragma unroll
  for (int off = 32; off > 0; off >>= 1) lmax = fmaxf(lmax, __shfl_xor(lmax, off));
  if (lane == 0) red[w] = lmax;
  __syncthreads();
  const float m = fmaxf(fmaxf(red[0], red[1]), fmaxf(red[2], red[3])) * LOG2E;
  __syncthreads();
  float lsum = 0.f;
  for (int j = tid * 4; j < Ltok; j += 1024) {
    lsum += exp2f(buf[j] * LOG2E - m) + exp2f(buf[j + 1] * LOG2E - m) +
            exp2f(buf[j + 2] * LOG2E - m) + exp2f(buf[j + 3] * LOG2E - m);
  }
#pragma unroll
  for (int off = 32; off > 0; off >>= 1) lsum += __shfl_xor(lsum, off);
  if (lane == 0) red[w] = lsum;
  __syncthreads();
  const float inv = 1.0f / (red[0] + red[1] + red[2] + red[3]);
  float* arf = Af + (size_t)blockIdx.x * Ltok;
  ushort* arb = Abf + (size_t)blockIdx.x * Ltok;
  for (int j = tid * 4; j < Ltok; j += 1024) {
    float4 aa;
    aa.x = exp2f(buf[j] * LOG2E - m) * inv;
    aa.y = exp2f(buf[j + 1] * LOG2E - m) * inv;
    aa.z = exp2f(buf[j + 2] * LOG2E - m) * inv;
    aa.w = exp2f(buf[j + 3] * LOG2E - m) * inv;
    *(float4*)&arf[j] = aa;
    ushort4 o; o.x = f2bf(aa.x); o.y = f2bf(aa.y); o.z = f2bf(aa.z); o.w = f2bf(aa.w);
    *(ushort4*)&arb[j] = o;
  }
}

// ---------------------------------------------------------------------------
extern "C" void kernel_launch(void* const* d_in, const int* in_sizes, int n_in,
                              void* d_out, int out_size, void* d_ws, size_t ws_size,
                              hipStream_t stream) {
  const float* tok = (const float*)d_in[0];
  const float* ecc = (const float*)d_in[1];
  const float* Gm  = (const float*)d_in[2];
  const float* Rm  = (const float*)d_in[3];
  const float* Wv  = (const float*)d_in[4];
  const float* bv  = (const float*)d_in[5];
  const float* Wo  = (const float*)d_in[6];
  const float* bo  = (const float*)d_in[7];
  const int*   pos = (const int*)d_in[8];
  const int*   dep = (const int*)d_in[9];

  float* out_f = (float*)d_out;                    // [L][D] f32
  float* A_f   = out_f + (size_t)Ltok * Dm;        // [L][L] f32
  float* S_f   = A_f + (size_t)Ltok * Ltok;        // [L][L] f32

  char* ws = (char*)d_ws;
  size_t off = 0;
  auto alloc = [&](size_t bytes) {
    void* p = ws + off; off = (off + bytes + 255) & ~(size_t)255; return p;
  };
  ushort* Tbf  = (ushort*)alloc((size_t)Ltok * Dm * 2);
  ushort* Wvbf = (ushort*)alloc((size_t)Dm * Dm * 2);
  ushort* Wobf = (ushort*)alloc((size_t)Dm * Dm * 2);
  ushort* Vt   = (ushort*)alloc((size_t)Dm * Ltok * 2);   // V^T [D][L]
  ushort* Abf  = (ushort*)alloc((size_t)Ltok * Ltok * 2);
  ushort* AVbf = (ushort*)alloc((size_t)Ltok * Dm * 2);
  float4* tokf4 = (float4*)alloc(Ltok * 16);
  float*  sGR  = (float*)alloc(64 * 4);

  prep_tokens<<<Ltok, 256, 0, stream>>>(tok, ecc, pos, dep, Tbf, tokf4);
  cast_f32_bf16<<<(Dm * Dm) / 1024, 256, 0, stream>>>(Wv, Wvbf, Dm * Dm);
  cast_f32_bf16<<<(Dm * Dm) / 1024, 256, 0, stream>>>(Wo, Wobf, Dm * Dm);
  small_prep<<<1, 64, 0, stream>>>(Gm, Rm, sGR);

  // scores = c_ij * (T @ T^T) -> f32
  // gemm4b: 16x32 = 512 blocks, 48KB LDS, <=128 VGPR  =>  2 blocks/CU
  gemm4b<0, Ltok, Dm><<<dim3(Ltok / 256, Ltok / 128), 512, 0, stream>>>(
      Tbf, Tbf, S_f, tokf4, sGR);
  softmax_rows<<<Ltok, 256, 0, stream>>>(S_f, A_f, Abf);

  // V^T[d][l] = Wv[d] . T[l] + bv[d]  -> bf16   (grid 16x16 = 256 blocks)
  gemm4<1, Ltok, Dm><<<dim3(Ltok / 256, Dm / 128), 512, 0, stream>>>(
      Wvbf, Tbf, nullptr, Vt, bv);

  // AV = A @ V (B^T = Vt) -> bf16   (grid 8x32 = 256 blocks)
  gemm4<2, Dm, Ltok><<<dim3(Dm / 256, Ltok / 128), 512, 0, stream>>>(
      Abf, Vt, nullptr, AVbf, nullptr);

  // out = AV @ Wo^T + bo -> f32   (grid 8x32 = 256 blocks)
  gemm4<3, Dm, Dm><<<dim3(Dm / 256, Ltok / 128), 512, 0, stream>>>(
      AVbf, Wobf, out_f, nullptr, bo);
}

// Round 11
// 234.092 us; speedup vs baseline: 1.1507x; 1.1507x over previous
//
#include <hip/hip_runtime.h>
#include <cstdint>

#define Ltok 4096
#define Dm   2048

typedef __attribute__((ext_vector_type(8))) short short8;
typedef __attribute__((ext_vector_type(4))) float f32x4;
typedef __attribute__((ext_vector_type(4))) int   i32x4;

static __device__ __forceinline__ ushort f2bf(float x) {
  union { float f; uint32_t u; } v; v.f = x;
  uint32_t r = v.u + 0x7FFFu + ((v.u >> 16) & 1u);
  return (ushort)(r >> 16);
}

typedef __attribute__((address_space(1))) void gv_t;
typedef __attribute__((address_space(3))) void lv_t;
static __device__ __forceinline__ void lds_load16(const void* g, void* l) {
  __builtin_amdgcn_global_load_lds((gv_t*)g, (lv_t*)l, 16, 0, 0);
}

// ---------------------------------------------------------------------------
__global__ __launch_bounds__(256) void prep_tokens(const float* __restrict__ T,
                                                   const float* __restrict__ ecc,
                                                   const int* __restrict__ pos,
                                                   const int* __restrict__ dep,
                                                   ushort* __restrict__ Tbf,
                                                   float4* __restrict__ tokf4) {
  __shared__ float red[4];
  const int tid = threadIdx.x, lane = tid & 63, w = tid >> 6;
  const int row = blockIdx.x;
  const float* rp = T + (size_t)row * Dm;
  ushort* op = Tbf + (size_t)row * Dm;
  float ss = 0.f;
  for (int j = tid * 4; j < Dm; j += 1024) {
    float4 v = *(const float4*)&rp[j];
    ss += v.x * v.x + v.y * v.y + v.z * v.z + v.w * v.w;
    ushort4 o; o.x = f2bf(v.x); o.y = f2bf(v.y); o.z = f2bf(v.z); o.w = f2bf(v.w);
    *(ushort4*)&op[j] = o;
  }
#pragma unroll
  for (int off = 32; off > 0; off >>= 1) ss += __shfl_xor(ss, off);
  if (lane == 0) red[w] = ss;
  __syncthreads();
  if (tid == 0) {
    float n = sqrtf(red[0] + red[1] + red[2] + red[3]);
    int d = dep[row];
    float4 t;
    t.x = n / (n + 1e-8f);
    t.y = ecc[row];
    t.z = (d <= 0) ? 1.0f : (d == 1 ? 3.0f : 9.0f);
    t.w = (float)pos[row];
    tokf4[row] = t;
  }
}

__global__ __launch_bounds__(256) void cast_f32_bf16(const float* __restrict__ in,
                                                     ushort* __restrict__ out, int n) {
  int i = (blockIdx.x * 256 + threadIdx.x) * 4;
  if (i + 3 < n) {
    float4 v = *(const float4*)&in[i];
    ushort4 o; o.x = f2bf(v.x); o.y = f2bf(v.y); o.z = f2bf(v.z); o.w = f2bf(v.w);
    *(ushort4*)&out[i] = o;
  }
}

__global__ void small_prep(const float* __restrict__ G, const float* __restrict__ R,
                           float* __restrict__ sGR) {
  int tid = threadIdx.x;
  if (tid < 64) {
    float g = 1.0f / (1.0f + expf(-G[tid]));
    float r = 1.0f / (1.0f + expf(-R[tid]));
    sGR[tid] = g * r;
  }
}

// ---------------------------------------------------------------------------
#define FENCE asm volatile("" ::: "memory")
#define PH_MID { FENCE; __builtin_amdgcn_s_barrier(); __builtin_amdgcn_s_setprio(1); }
#define PH_END { __builtin_amdgcn_s_setprio(0); FENCE; __builtin_amdgcn_s_barrier(); FENCE; }
#define PH_ENDV { __builtin_amdgcn_s_setprio(0); FENCE; \
                  asm volatile("s_waitcnt vmcnt(6)" ::: "memory"); \
                  __builtin_amdgcn_s_barrier(); FENCE; }
#define PH_ENDV1 { __builtin_amdgcn_s_setprio(0); FENCE; \
                  asm volatile("s_waitcnt vmcnt(1)" ::: "memory"); \
                  __builtin_amdgcn_s_barrier(); FENCE; }
#define PH_ENDV2 { __builtin_amdgcn_s_setprio(0); FENCE; \
                  asm volatile("s_waitcnt vmcnt(2)" ::: "memory"); \
                  __builtin_amdgcn_s_barrier(); FENCE; }

// inverse st_16x32 swizzle within a 16KB unit (two 8KB halves x 2 col-blocks)
#define INV_SWZ(P, ROW, COL) { \
  int s_ = (P) >> 10, ww_ = (P) & 1023; \
  ww_ ^= ((ww_ >> 9) & 1) << 5; \
  ROW = ((s_ >> 1) << 4) + (ww_ >> 6); \
  COL = ((s_ & 1) << 5) + ((ww_ >> 1) & 31); }

// inverse swizzle within an 8KB unit, byte-addressed ([128 rows][64 bytes])
#define INV_SWZ8B(P, ROW, COLB) { \
  int s_ = (P) >> 10, ww_ = (P) & 1023; \
  ww_ ^= ((ww_ >> 9) & 1) << 5; \
  ROW = (s_ << 4) + (ww_ >> 6); \
  COLB = ww_ & 63; }

// ===========================================================================
// gemm8: 256x256 tile (BK=64, 8 waves 2Mx4N, per-wave 128x64), 8-phase.
// (round-6 proven form, MODE 0 scores only)
#define ST_A(BUF,H,KT) { \
  lds_load16(sA0 + (size_t)(H)*128*KDIM + (size_t)(KT)*64, lbase + (BUF)*65536 + (H)*16384 + stW); \
  lds_load16(sA1 + (size_t)(H)*128*KDIM + (size_t)(KT)*64, lbase + (BUF)*65536 + (H)*16384 + 8192 + stW); }
#define ST_B(BUF,H,KT) { \
  lds_load16(sB0 + (size_t)(H)*128*KDIM + (size_t)(KT)*64, lbase + (BUF)*65536 + 32768 + (H)*16384 + stW); \
  lds_load16(sB1 + (size_t)(H)*128*KDIM + (size_t)(KT)*64, lbase + (BUF)*65536 + 32768 + (H)*16384 + 8192 + stW); }
#define DS_A(BUF,MIB) { _Pragma("unroll") for (int m_ = 0; m_ < 4; ++m_) \
  _Pragma("unroll") for (int kk_ = 0; kk_ < 2; ++kk_) \
    a[m_][kk_] = *(const short8*)(lbase + (BUF)*65536 + baseA + ((MIB)+m_)*2048 + kk_*1024); }
#define DS_B(BUF,NIB) { _Pragma("unroll") for (int n_ = 0; n_ < 2; ++n_) \
  _Pragma("unroll") for (int kk_ = 0; kk_ < 2; ++kk_) \
    bq[(NIB)+n_][kk_] = *(const short8*)(lbase + (BUF)*65536 + 32768 + baseB + ((NIB)+n_)*2048 + kk_*1024); }
#define MFMA_Q(MIB,NIB) { _Pragma("unroll") for (int m_ = 0; m_ < 4; ++m_) \
  _Pragma("unroll") for (int n_ = 0; n_ < 2; ++n_) { \
    acc[(MIB)+m_][(NIB)+n_] = __builtin_amdgcn_mfma_f32_16x16x32_bf16(a[m_][0], bq[(NIB)+n_][0], acc[(MIB)+m_][(NIB)+n_], 0, 0, 0); \
    acc[(MIB)+m_][(NIB)+n_] = __builtin_amdgcn_mfma_f32_16x16x32_bf16(a[m_][1], bq[(NIB)+n_][1], acc[(MIB)+m_][(NIB)+n_], 0, 0, 0); } }

template <int NDIM, int KDIM>
__global__ __launch_bounds__(512, 2) void gemm8(
    const ushort* __restrict__ A, const ushort* __restrict__ B,
    float* __restrict__ Cf,
    const float4* __restrict__ tokf4, const float* __restrict__ sGR)
{
  constexpr int NT = KDIM / 64;
  constexpr int NI = NT / 2;
  __shared__ __align__(16) char lds_raw[131072];
  char* lbase = lds_raw;

  const int tid = threadIdx.x;
  const int lane = tid & 63;
  const int w0 = tid >> 6;
  const int wr = w0 >> 2, wc = w0 & 3;
  const int fr = lane & 15, fq = lane >> 4;

  int gx = gridDim.x;
  int bid = blockIdx.y * gx + blockIdx.x;
  int cpx = (gx * gridDim.y) >> 3;
  int sbid = (bid & 7) * cpx + (bid >> 3);
  const int bn = (sbid % gx) * 256;
  const int bm = (sbid / gx) * 256;

  int rA0, cA0, rA1, cA1;
  INV_SWZ(tid * 16, rA0, cA0)
  INV_SWZ(tid * 16 + 8192, rA1, cA1)
  const ushort* sA0 = A + (size_t)(bm + rA0) * KDIM + cA0;
  const ushort* sA1 = A + (size_t)(bm + rA1) * KDIM + cA1;
  const ushort* sB0 = B + (size_t)(bn + rA0) * KDIM + cA0;
  const ushort* sB1 = B + (size_t)(bn + rA1) * KDIM + cA1;
  const int stW = w0 * 1024;

  const int lanep = (fr * 64 + fq * 16) ^ ((fr & 8) << 2);
  const int baseA = wr * 16384 + lanep;
  const int baseB = wc * 8192 + lanep;

  short8 a[4][2], bq[4][2];
  f32x4 acc[8][4] = {};

  ST_A(0, 0, 0) ST_A(0, 1, 0) ST_B(0, 0, 0) ST_B(0, 1, 0)
  ST_B(1, 0, 1) ST_A(1, 0, 1) ST_A(1, 1, 1)
  FENCE;
  asm volatile("s_waitcnt vmcnt(6)" ::: "memory");
  __builtin_amdgcn_s_barrier();
  FENCE;

#pragma unroll 1
  for (int it = 0; it < NI; ++it) {
    const int t1 = 2 * it + 1;
    const int t2 = (2 * it + 2 < NT) ? 2 * it + 2 : NT - 1;
    const int t3 = (2 * it + 3 < NT) ? 2 * it + 3 : NT - 1;
    DS_A(0, 0) DS_B(0, 0) ST_B(1, 1, t1)
    PH_MID MFMA_Q(0, 0) PH_END
    DS_B(0, 2)
    PH_MID MFMA_Q(0, 2) PH_END
    DS_A(0, 4) ST_B(0, 0, t2)
    PH_MID MFMA_Q(4, 2) PH_END
    ST_B(0, 1, t2) ST_A(0, 0, t2)
    PH_MID MFMA_Q(4, 0) PH_ENDV
    DS_A(1, 0) DS_B(1, 0) ST_A(0, 1, t2)
    PH_MID MFMA_Q(0, 0) PH_END
    DS_B(1, 2)
    PH_MID MFMA_Q(0, 2) PH_END
    DS_A(1, 4) ST_B(1, 0, t3)
    PH_MID MFMA_Q(4, 2) PH_END
    ST_A(1, 0, t3) ST_A(1, 1, t3)
    PH_MID MFMA_Q(4, 0) PH_ENDV
  }

  // ---- epilogue: scores ----
  const int gj0 = bn + wc * 64 + fr;
  const int gi0 = bm + wr * 128 + fq * 4;
  float4 cj[4];
#pragma unroll
  for (int n = 0; n < 4; ++n) cj[n] = tokf4[gj0 + n * 16];
#pragma unroll
  for (int m = 0; m < 8; ++m) {
#pragma unroll
    for (int r = 0; r < 4; ++r) {
      const int gi = gi0 + m * 16 + r;
      float4 ci = tokf4[gi];
#pragma unroll
      for (int n = 0; n < 4; ++n) {
        const int gj = gj0 + n * 16;
        float x = acc[m][n][r];
        float rr = fabsf(ci.z - cj[n].z) + 1.0f;
        int pi = (int)ci.w, pj = (int)cj[n].w;
        float c = sGR[pi * 8 + pj] * (1.0f - ci.y * cj[n].y) *
                  (ci.x * cj[n].x) * __builtin_amdgcn_rcpf(rr * rr);
        x *= c;
        if (gi == gj) x = 0.0f;
        Cf[(size_t)gi * NDIM + gj] = x;
      }
    }
  }
}

// ===========================================================================
// gemm4: 128x256 tile bf16 (BK=64, 8 waves, per-wave 64x64), 4-phase.
// MODE 1: +row bias -> i8 quant (x 127/8, clamp) for V^T.
// MODE 3: +col bias -> f32 for out.
#define ST_A4(BUF,KT) { \
  lds_load16(sA0 + (size_t)(KT)*64, lbase + (BUF)*49152 + stW); \
  lds_load16(sA1 + (size_t)(KT)*64, lbase + (BUF)*49152 + 8192 + stW); }
#define ST_B4(BUF,H,KT) { \
  lds_load16(sB0 + (size_t)(H)*128*KDIM + (size_t)(KT)*64, lbase + (BUF)*49152 + 16384 + (H)*16384 + stW); \
  lds_load16(sB1 + (size_t)(H)*128*KDIM + (size_t)(KT)*64, lbase + (BUF)*49152 + 16384 + (H)*16384 + 8192 + stW); }
#define DS_A4(BUF) { _Pragma("unroll") for (int m_ = 0; m_ < 4; ++m_) \
  _Pragma("unroll") for (int kk_ = 0; kk_ < 2; ++kk_) \
    a[m_][kk_] = *(const short8*)(lbase + (BUF)*49152 + baseA + m_*2048 + kk_*1024); }
#define DS_B4(BUF,NIB) { _Pragma("unroll") for (int n_ = 0; n_ < 2; ++n_) \
  _Pragma("unroll") for (int kk_ = 0; kk_ < 2; ++kk_) \
    bq[(NIB)+n_][kk_] = *(const short8*)(lbase + (BUF)*49152 + 16384 + baseB + ((NIB)+n_)*2048 + kk_*1024); }
#define MFMA_Q4(NIB) { _Pragma("unroll") for (int m_ = 0; m_ < 4; ++m_) \
  _Pragma("unroll") for (int n_ = 0; n_ < 2; ++n_) { \
    acc[m_][(NIB)+n_] = __builtin_amdgcn_mfma_f32_16x16x32_bf16(a[m_][0], bq[(NIB)+n_][0], acc[m_][(NIB)+n_], 0, 0, 0); \
    acc[m_][(NIB)+n_] = __builtin_amdgcn_mfma_f32_16x16x32_bf16(a[m_][1], bq[(NIB)+n_][1], acc[m_][(NIB)+n_], 0, 0, 0); } }

template <int MODE, int NDIM, int KDIM>
__global__ __launch_bounds__(512, 2) void gemm4(
    const ushort* __restrict__ A, const ushort* __restrict__ B,
    float* __restrict__ Cf, signed char* __restrict__ C8,
    const float* __restrict__ bias)
{
  constexpr int NT = KDIM / 64;
  constexpr int NI = NT / 2;
  __shared__ __align__(16) char lds_raw[98304];
  char* lbase = lds_raw;

  const int tid = threadIdx.x;
  const int lane = tid & 63;
  const int w0 = tid >> 6;
  const int wr = w0 >> 2, wc = w0 & 3;
  const int fr = lane & 15, fq = lane >> 4;

  int gx = gridDim.x;
  int bid = blockIdx.y * gx + blockIdx.x;
  int cpx = (gx * gridDim.y) >> 3;
  int sbid = (bid & 7) * cpx + (bid >> 3);
  const int bn = (sbid % gx) * 256;
  const int bm = (sbid / gx) * 128;

  int rA0, cA0, rA1, cA1;
  INV_SWZ(tid * 16, rA0, cA0)
  INV_SWZ(tid * 16 + 8192, rA1, cA1)
  const ushort* sA0 = A + (size_t)(bm + rA0) * KDIM + cA0;
  const ushort* sA1 = A + (size_t)(bm + rA1) * KDIM + cA1;
  const ushort* sB0 = B + (size_t)(bn + rA0) * KDIM + cA0;
  const ushort* sB1 = B + (size_t)(bn + rA1) * KDIM + cA1;
  const int stW = w0 * 1024;

  const int lanep = (fr * 64 + fq * 16) ^ ((fr & 8) << 2);
  const int baseA = wr * 8192 + lanep;
  const int baseB = wc * 8192 + lanep;

  short8 a[4][2], bq[4][2];
  f32x4 acc[4][4] = {};

  ST_A4(0, 0) ST_B4(0, 0, 0) ST_B4(0, 1, 0)
  ST_A4(1, 1)
  FENCE;
  asm volatile("s_waitcnt vmcnt(2)" ::: "memory");
  __builtin_amdgcn_s_barrier();
  FENCE;

#pragma unroll 1
  for (int it = 0; it < NI; ++it) {
    const int t1 = 2 * it + 1;
    const int t2 = (2 * it + 2 < NT) ? 2 * it + 2 : NT - 1;
    const int t3 = (2 * it + 3 < NT) ? 2 * it + 3 : NT - 1;
    DS_A4(0) DS_B4(0, 0) ST_B4(1, 0, t1) ST_B4(1, 1, t1)
    PH_MID MFMA_Q4(0) PH_END
    DS_B4(0, 2) ST_A4(0, t2)
    PH_MID MFMA_Q4(2) PH_ENDV2
    DS_A4(1) DS_B4(1, 0) ST_B4(0, 0, t2) ST_B4(0, 1, t2)
    PH_MID MFMA_Q4(0) PH_END
    DS_B4(1, 2) ST_A4(1, t3)
    PH_MID MFMA_Q4(2) PH_ENDV2
  }

  // ---- epilogue ----
  const int gj0 = bn + wc * 64 + fr;
  const int gi0 = bm + wr * 64 + fq * 4;

  if constexpr (MODE == 1) {
#pragma unroll
    for (int m = 0; m < 4; ++m) {
#pragma unroll
      for (int r = 0; r < 4; ++r) {
        const int gi = gi0 + m * 16 + r;
        float rb = bias[gi];
#pragma unroll
        for (int n = 0; n < 4; ++n) {
          float x = (acc[m][n][r] + rb) * 15.875f;          // 127/8
          x = fminf(fmaxf(x, -127.0f), 127.0f);
          C8[(size_t)gi * NDIM + gj0 + n * 16] = (signed char)(int)rintf(x);
        }
      }
    }
  } else {
    float cb[4];
#pragma unroll
    for (int n = 0; n < 4; ++n) cb[n] = bias[gj0 + n * 16];
#pragma unroll
    for (int m = 0; m < 4; ++m)
#pragma unroll
      for (int r = 0; r < 4; ++r) {
        const int gi = gi0 + m * 16 + r;
#pragma unroll
        for (int n = 0; n < 4; ++n)
          Cf[(size_t)gi * NDIM + gj0 + n * 16] = acc[m][n][r] + cb[n];
      }
  }
}

// ===========================================================================
// gemm4i: i8 AV GEMM.  128x256 tile, BK=64 i8, 8 waves, 4-phase, 48KB LDS.
// Byte-layout identical to proven gemm4b skeleton: A-unit 8KB = [128r][64B]
// @0; B 2x8KB @8192; buf stride 24576; vmcnt(1) drains.
// AV[l][d] = (sum qA[l][k] qV[d][k]) * sRow[l] * (8/127), -> bf16.
#define STI_A(BUF,KT) \
  lds_load16(sAs + (size_t)(KT)*64, lbase + (BUF)*24576 + tid*16);
#define STI_BH(BUF,H,KT) \
  lds_load16(sBs + (size_t)(H)*128*KDIM + (size_t)(KT)*64, lbase + (BUF)*24576 + 8192 + (H)*8192 + tid*16);
#define RDI_A(BUF) { _Pragma("unroll") for (int m_ = 0; m_ < 4; ++m_) \
    ai[m_] = *(const i32x4*)(lbase + (BUF)*24576 + baseA + m_*1024); }
#define RDI_B(BUF,NIB) { _Pragma("unroll") for (int n_ = 0; n_ < 2; ++n_) \
    bi[n_] = *(const i32x4*)(lbase + (BUF)*24576 + baseB + ((NIB)+n_)*1024); }
#define MFI_P(NIB) { _Pragma("unroll") for (int m_ = 0; m_ < 4; ++m_) \
  _Pragma("unroll") for (int n_ = 0; n_ < 2; ++n_) \
    acc[m_][(NIB)+n_] = __builtin_amdgcn_mfma_i32_16x16x64_i8(ai[m_], bi[n_], acc[m_][(NIB)+n_], 0, 0, 0); }

template <int NDIM, int KDIM>
__global__ __launch_bounds__(512, 2) void gemm4i(
    const signed char* __restrict__ A, const signed char* __restrict__ B,
    ushort* __restrict__ Cbf, const float* __restrict__ sRow)
{
  constexpr int NT = KDIM / 64;
  constexpr int NI = NT / 2;
  __shared__ __align__(16) char lds_raw[49152];
  char* lbase = lds_raw;

  const int tid = threadIdx.x;
  const int lane = tid & 63;
  const int w0 = tid >> 6;
  const int wr = w0 >> 2, wc = w0 & 3;
  const int fr = lane & 15, fq = lane >> 4;

  int gx = gridDim.x;
  int bid = blockIdx.y * gx + blockIdx.x;
  int cpx = (gx * gridDim.y) >> 3;
  int sbid = (bid & 7) * cpx + (bid >> 3);
  const int bn = (sbid % gx) * 256;
  const int bm = (sbid / gx) * 128;

  int rS, cSB;
  INV_SWZ8B(tid * 16, rS, cSB)
  const signed char* sAs = A + (size_t)(bm + rS) * KDIM + cSB;
  const signed char* sBs = B + (size_t)(bn + rS) * KDIM + cSB;

  const int lanep = (fr * 64 + fq * 16) ^ ((fr & 8) << 2);
  const int baseA = wr * 4096 + lanep;
  const int baseB = 8192 + wc * 4096 + lanep;

  i32x4 ai[4], bi[2];
  i32x4 acc[4][4] = {};

  STI_A(0, 0) STI_BH(0, 0, 0) STI_BH(0, 1, 0)
  STI_A(1, 1)
  FENCE;
  asm volatile("s_waitcnt vmcnt(1)" ::: "memory");
  __builtin_amdgcn_s_barrier();
  FENCE;

#pragma unroll 1
  for (int it = 0; it < NI; ++it) {
    const int t1 = 2 * it + 1;
    const int t2 = (2 * it + 2 < NT) ? 2 * it + 2 : NT - 1;
    const int t3 = (2 * it + 3 < NT) ? 2 * it + 3 : NT - 1;
    RDI_A(0) RDI_B(0, 0) STI_BH(1, 0, t1) STI_BH(1, 1, t1)
    PH_MID MFI_P(0) PH_END
    RDI_B(0, 2) STI_A(0, t2)
    PH_MID MFI_P(2) PH_ENDV1
    RDI_A(1) RDI_B(1, 0) STI_BH(0, 0, t2) STI_BH(0, 1, t2)
    PH_MID MFI_P(0) PH_END
    RDI_B(1, 2) STI_A(1, t3)
    PH_MID MFI_P(2) PH_ENDV1
  }

  // ---- epilogue: dequant -> bf16 ----
  const int gj0 = bn + wc * 64 + fr;
  const int gi0 = bm + wr * 64 + fq * 4;
  const float sV = 8.0f / 127.0f;
#pragma unroll
  for (int m = 0; m < 4; ++m) {
#pragma unroll
    for (int r = 0; r < 4; ++r) {
      const int gi = gi0 + m * 16 + r;
      float sa = sRow[gi] * sV;
#pragma unroll
      for (int n = 0; n < 4; ++n)
        Cbf[(size_t)gi * NDIM + gj0 + n * 16] = f2bf((float)acc[m][n][r] * sa);
    }
  }
}

// ---------------------------------------------------------------------------
// softmax: f32 A -> d_out, i8 A (q = round(exp*127)) + row scale -> ws
__global__ __launch_bounds__(256) void softmax_rows(const float* __restrict__ S,
                                                    float* __restrict__ Af,
                                                    signed char* __restrict__ Aq,
                                                    float* __restrict__ sRowA) {
  __shared__ float buf[Ltok];
  __shared__ float red[4];
  const int tid = threadIdx.x, lane = tid & 63, w = tid >> 6;
  const float LOG2E = 1.44269504088896f;
  const float* sr = S + (size_t)blockIdx.x * Ltok;
  float lmax = -3.4e38f;
  for (int j = tid * 4; j < Ltok; j += 1024) {
    float4 v = *(const float4*)&sr[j];
    *(float4*)&buf[j] = v;
    lmax = fmaxf(fmaxf(lmax, fmaxf(v.x, v.y)), fmaxf(v.z, v.w));
  }
#pragma unroll
  for (int off = 32; off > 0; off >>= 1) lmax = fmaxf(lmax, __shfl_xor(lmax, off));
  if (lane == 0) red[w] = lmax;
  __syncthreads();
  const float m = fmaxf(fmaxf(red[0], red[1]), fmaxf(red[2], red[3])) * LOG2E;
  __syncthreads();
  float lsum = 0.f;
  for (int j = tid * 4; j < Ltok; j += 1024) {
    lsum += exp2f(buf[j] * LOG2E - m) + exp2f(buf[j + 1] * LOG2E - m) +
            exp2f(buf[j + 2] * LOG2E - m) + exp2f(buf[j + 3] * LOG2E - m);
  }
#pragma unroll
  for (int off = 32; off > 0; off >>= 1) lsum += __shfl_xor(lsum, off);
  if (lane == 0) red[w] = lsum;
  __syncthreads();
  const float inv = 1.0f / (red[0] + red[1] + red[2] + red[3]);
  if (tid == 0) sRowA[blockIdx.x] = inv * (1.0f / 127.0f);
  float* arf = Af + (size_t)blockIdx.x * Ltok;
  signed char* arq = Aq + (size_t)blockIdx.x * Ltok;
  for (int j = tid * 4; j < Ltok; j += 1024) {
    float e0 = exp2f(buf[j] * LOG2E - m);
    float e1 = exp2f(buf[j + 1] * LOG2E - m);
    float e2 = exp2f(buf[j + 2] * LOG2E - m);
    float e3 = exp2f(buf[j + 3] * LOG2E - m);
    float4 aa; aa.x = e0 * inv; aa.y = e1 * inv; aa.z = e2 * inv; aa.w = e3 * inv;
    *(float4*)&arf[j] = aa;
    char4 q;
    q.x = (signed char)(int)rintf(e0 * 127.0f);
    q.y = (signed char)(int)rintf(e1 * 127.0f);
    q.z = (signed char)(int)rintf(e2 * 127.0f);
    q.w = (signed char)(int)rintf(e3 * 127.0f);
    *(char4*)&arq[j] = q;
  }
}

// ---------------------------------------------------------------------------
extern "C" void kernel_launch(void* const* d_in, const int* in_sizes, int n_in,
                              void* d_out, int out_size, void* d_ws, size_t ws_size,
                              hipStream_t stream) {
  const float* tok = (const float*)d_in[0];
  const float* ecc = (const float*)d_in[1];
  const float* Gm  = (const float*)d_in[2];
  const float* Rm  = (const float*)d_in[3];
  const float* Wv  = (const float*)d_in[4];
  const float* bv  = (const float*)d_in[5];
  const float* Wo  = (const float*)d_in[6];
  const float* bo  = (const float*)d_in[7];
  const int*   pos = (const int*)d_in[8];
  const int*   dep = (const int*)d_in[9];

  float* out_f = (float*)d_out;                    // [L][D] f32
  float* A_f   = out_f + (size_t)Ltok * Dm;        // [L][L] f32
  float* S_f   = A_f + (size_t)Ltok * Ltok;        // [L][L] f32

  char* ws = (char*)d_ws;
  size_t off = 0;
  auto alloc = [&](size_t bytes) {
    void* p = ws + off; off = (off + bytes + 255) & ~(size_t)255; return p;
  };
  ushort* Tbf  = (ushort*)alloc((size_t)Ltok * Dm * 2);
  ushort* Wvbf = (ushort*)alloc((size_t)Dm * Dm * 2);
  ushort* Wobf = (ushort*)alloc((size_t)Dm * Dm * 2);
  signed char* Vtq = (signed char*)alloc((size_t)Dm * Ltok);  // V^T i8 [D][L]
  signed char* Aq  = (signed char*)alloc((size_t)Ltok * Ltok); // A i8 [L][L]
  ushort* AVbf = (ushort*)alloc((size_t)Ltok * Dm * 2);
  float4* tokf4 = (float4*)alloc(Ltok * 16);
  float*  sGR  = (float*)alloc(64 * 4);
  float*  sRowA = (float*)alloc(Ltok * 4);

  prep_tokens<<<Ltok, 256, 0, stream>>>(tok, ecc, pos, dep, Tbf, tokf4);
  cast_f32_bf16<<<(Dm * Dm) / 1024, 256, 0, stream>>>(Wv, Wvbf, Dm * Dm);
  cast_f32_bf16<<<(Dm * Dm) / 1024, 256, 0, stream>>>(Wo, Wobf, Dm * Dm);
  small_prep<<<1, 64, 0, stream>>>(Gm, Rm, sGR);

  // scores = c_ij * (T @ T^T) -> f32   (gemm8, 256 blocks)
  gemm8<Ltok, Dm><<<dim3(Ltok / 256, Ltok / 256), 512, 0, stream>>>(
      Tbf, Tbf, S_f, tokf4, sGR);
  // A = softmax(scores): f32 -> d_out, i8 + row scale -> ws
  softmax_rows<<<Ltok, 256, 0, stream>>>(S_f, A_f, Aq, sRowA);

  // V^T[d][l] = Wv[d].T[l] + bv[d] -> i8 (x 127/8)   (grid 16x16)
  gemm4<1, Ltok, Dm><<<dim3(Ltok / 256, Dm / 128), 512, 0, stream>>>(
      Wvbf, Tbf, nullptr, Vtq, bv);

  // AV = A @ V in i8 -> bf16   (grid 8x32 = 256 blocks)
  gemm4i<Dm, Ltok><<<dim3(Dm / 256, Ltok / 128), 512, 0, stream>>>(
      Aq, Vtq, AVbf, sRowA);

  // out = AV @ Wo^T + bo -> f32   (grid 8x32 = 256 blocks)
  gemm4<3, Dm, Dm><<<dim3(Dm / 256, Ltok / 128), 512, 0, stream>>>(
      AVbf, Wobf, out_f, nullptr, bo);
}